// Round 1
// baseline (2566.404 us; speedup 1.0000x reference)
//
#include <hip/hip_runtime.h>
#include <math.h>

// Problem: B = T = 1000, N = 128, D = 64.
// All B batch rows evolve identically (zero init + broadcast input), so we
// simulate ONE row in f64 and broadcast. Output-write-bound: ~1.024 GB.

#define CHUNK 32  // input-current staging chunk (steps) in LDS

// ---------------------------------------------------------------------------
// Kernel 1: inp_cur[t][n] = sum_d sig[t][d] * win[d][n]  (float64 accumulate)
// grid = nt blocks, block = N threads.
// ---------------------------------------------------------------------------
__global__ void inpcur_kernel(const float* __restrict__ sig,
                              const float* __restrict__ win,
                              double* __restrict__ inp_cur,
                              int D, int N) {
    const int t = blockIdx.x;
    const int n = threadIdx.x;
    const float* srow = sig + (size_t)t * D;
    double acc = 0.0;
    for (int d = 0; d < D; ++d)
        acc += (double)srow[d] * (double)win[(size_t)d * N + n];
    inp_cur[(size_t)t * N + n] = acc;
}

// ---------------------------------------------------------------------------
// Kernel 2: sequential 1000-step LIF scan, one block of 128 threads
// (thread n owns neuron n). State in f64. Sparse recurrent update:
//   rec_{t+1} = TRACE_DECAY * rec_t + sum_{k spiked at t} Wrec[k][n]
// Writes compact spk/mem histories into row 0 of each output region,
// and final trace into row 0 of the trace region.
// ---------------------------------------------------------------------------
__global__ __launch_bounds__(128, 1) void sim_kernel(
    const double* __restrict__ inp_cur,
    const float* __restrict__ wrec,
    float* __restrict__ spk_out,    // d_out + 0           (row 0 of spikes)
    float* __restrict__ mem_out,    // d_out + B*TN        (row 0 of membrane)
    float* __restrict__ trace_out,  // d_out + 2*B*TN      (row 0 of trace)
    int nt) {
    __shared__ double x_lds[CHUNK][128];
    __shared__ unsigned long long masks[2][2];  // [t parity][wave]

    const int n = threadIdx.x;       // neuron id, 0..127
    const int w = n >> 6;            // wave id, 0..1

    double mem = 0.0, syn = 0.0, trace = 0.0, refr = 0.0, rec = 0.0;

    for (int t0 = 0; t0 < nt; t0 += CHUNK) {
        const int cs = (nt - t0 < CHUNK) ? (nt - t0) : CHUNK;
        // Stage this chunk's input currents: cs coalesced loads issued
        // back-to-back -> one HBM/L2 latency amortized over cs steps.
        for (int s = 0; s < cs; ++s)
            x_lds[s][n] = inp_cur[(size_t)(t0 + s) * 128 + n];
        __syncthreads();

        for (int s = 0; s < cs; ++s) {
            const int t = t0 + s;
            const double x = x_lds[s][n];

            // syn = syn*(1-1/TAU_SYN) + x + rec ; mem = mem*(1-1/TAU_MEM) + syn/TAU_MEM
            syn = syn * (1.0 - 1.0 / 5.0) + x + rec;
            mem = mem * (1.0 - 1.0 / 10.0) + syn / 10.0;
            if (refr > 0.0) mem = 0.0;          // refractory masking
            refr = refr - 1.0;
            if (refr < 0.0) refr = 0.0;
            const bool spike = mem > 1.0;

            const unsigned long long bal = __ballot(spike);
            if ((n & 63) == 0) masks[t & 1][w] = bal;

            if (spike) { mem = 0.0; refr += 2.0; }
            trace = trace * 0.95 + (spike ? 1.0 : 0.0);

            spk_out[(size_t)t * 128 + n] = spike ? 1.0f : 0.0f;
            mem_out[(size_t)t * 128 + n] = (float)mem;

            __syncthreads();  // masks visible to both waves

            // Sparse recurrent update: add Wrec[k][n] for every spiking k.
            double add = 0.0;
            unsigned long long m0 = masks[t & 1][0];
            unsigned long long m1 = masks[t & 1][1];
            while (m0) {
                const int k = __builtin_ctzll(m0);
                m0 &= m0 - 1;
                add += (double)wrec[(size_t)k * 128 + n];
            }
            while (m1) {
                const int k = __builtin_ctzll(m1);
                m1 &= m1 - 1;
                add += (double)wrec[(size_t)(k + 64) * 128 + n];
            }
            rec = rec * 0.95 + add;
        }
        __syncthreads();  // safety: chunk staging WAR
    }
    trace_out[n] = (float)trace;
}

// ---------------------------------------------------------------------------
// Kernel 3: broadcast compact row 0 -> rows 1..B-1 for spikes and membrane.
// grid = (ceil(TN/4/256), B-1), block = 256. float4 copies; row 0 stays hot
// in L2 so this is ~1.02 GB of pure HBM writes.
// ---------------------------------------------------------------------------
__global__ void bcast_kernel(float* __restrict__ out,
                             int TN4, long long TN, long long B_TN) {
    const long long b = (long long)blockIdx.y + 1;
    const int i = blockIdx.x * blockDim.x + threadIdx.x;
    if (i >= TN4) return;
    const float4 s = ((const float4*)out)[i];
    const float4 m = ((const float4*)(out + B_TN))[i];
    ((float4*)(out + b * TN))[i] = s;
    ((float4*)(out + B_TN + b * TN))[i] = m;
}

// ---------------------------------------------------------------------------
// Kernel 4: broadcast final trace row 0 -> rows 1..B-1.
// ---------------------------------------------------------------------------
__global__ void trace_bcast_kernel(float* __restrict__ tr, int B, int N4) {
    const int idx = blockIdx.x * blockDim.x + threadIdx.x;
    const int total = (B - 1) * N4;
    if (idx >= total) return;
    const int b = idx / N4 + 1;
    const int j = idx - (b - 1) * N4;
    ((float4*)(tr + (size_t)b * N4 * 4))[j] = ((const float4*)tr)[j];
}

// ---------------------------------------------------------------------------
extern "C" void kernel_launch(void* const* d_in, const int* in_sizes, int n_in,
                              void* d_out, int out_size, void* d_ws, size_t ws_size,
                              hipStream_t stream) {
    const float* sig  = (const float*)d_in[0];  // (T, D)
    const float* win  = (const float*)d_in[1];  // (D, N)
    const float* wrec = (const float*)d_in[2];  // (N, N)
    // d_in[3] = n_timesteps (device int); derived from sizes instead.

    // Derive dims: N from N*N, D from D*N, T (=B) from T*D, nt from out_size.
    int N = 1;
    while ((long long)N * N < (long long)in_sizes[2]) ++N;   // N = 128
    const int D = in_sizes[1] / N;                            // 64
    const int B = in_sizes[0] / D;                            // 1000 (= T)
    const int nt = (int)((((long long)out_size / B) - N) / (2 * N));  // 1000

    const long long TN   = (long long)nt * N;   // 128,000
    const long long B_TN = (long long)B * TN;   // 128,000,000

    float* out = (float*)d_out;
    // Scratch for f64 input currents: tail of d_out (2*TN float slots =
    // TN doubles). Entirely overwritten later by bcast/trace_bcast, and the
    // sim kernel's final trace write happens after its last inp_cur read.
    double* inp_cur = (double*)(out + ((size_t)out_size - 2 * (size_t)TN));

    inpcur_kernel<<<nt, N, 0, stream>>>(sig, win, inp_cur, D, N);

    sim_kernel<<<1, 128, 0, stream>>>(inp_cur, wrec,
                                      out,              // spikes row 0
                                      out + B_TN,       // membrane row 0
                                      out + 2 * B_TN,   // trace row 0
                                      nt);

    const int TN4 = (int)(TN / 4);
    dim3 bgrid((TN4 + 255) / 256, B - 1);
    bcast_kernel<<<bgrid, 256, 0, stream>>>(out, TN4, TN, B_TN);

    const int trace_total = (B - 1) * (N / 4);
    trace_bcast_kernel<<<(trace_total + 255) / 256, 256, 0, stream>>>(
        out + 2 * B_TN, B, N / 4);
}

// Round 3
// 1925.025 us; speedup vs baseline: 1.3332x; 1.3332x over previous
//
#include <hip/hip_runtime.h>
#include <math.h>

// B = T = 1000, N = 128, D = 64. All batch rows identical -> simulate one row
// in f64, broadcast. Sim = single wave (64 lanes, 2 neurons/lane): no
// barriers, spike masks live in SGPRs via __ballot, wrec in LDS.

#define XCHUNK 8   // input-current register prefetch depth (steps)

typedef float vf4 __attribute__((ext_vector_type(4)));  // clang-native float4

// ---------------------------------------------------------------------------
// Kernel 1: inp_cur[t][n] = sum_d sig[t][d] * win[d][n]  (float64 accumulate)
// UNCHANGED from the passing round (bit-exact reproducibility).
// ---------------------------------------------------------------------------
__global__ void inpcur_kernel(const float* __restrict__ sig,
                              const float* __restrict__ win,
                              double* __restrict__ inp_cur,
                              int D, int N) {
    const int t = blockIdx.x;
    const int n = threadIdx.x;
    const float* srow = sig + (size_t)t * D;
    double acc = 0.0;
    for (int d = 0; d < D; ++d)
        acc += (double)srow[d] * (double)win[(size_t)d * N + n];
    inp_cur[(size_t)t * N + n] = acc;
}

// ---------------------------------------------------------------------------
// Kernel 2: 1000-step LIF scan, ONE wave (64 threads). Lane l owns neurons
// l and l+64. f64 state; sparse recurrent update with wave-uniform masks.
// Per-neuron arithmetic order identical to the round-1 passing kernel.
// ---------------------------------------------------------------------------
__global__ __launch_bounds__(64, 1) void sim_kernel(
    const double* __restrict__ inp_cur,
    const float* __restrict__ wrec,
    float* __restrict__ spk_out,    // row 0 of spikes region
    float* __restrict__ mem_out,    // row 0 of membrane region
    float* __restrict__ trace_out,  // row 0 of trace region
    int nt) {
    __shared__ float lds_w[128 * 128];  // 64 KiB: wrec row-major

    const int l = threadIdx.x;  // lane 0..63

    // Stage wrec into LDS: 16384 floats, float4-vectorized, coalesced.
    {
        const vf4* src = (const vf4*)wrec;
        vf4* dst = (vf4*)lds_w;
        for (int i = 0; i < 64; ++i)
            dst[i * 64 + l] = src[i * 64 + l];
        // Same-wave LDS RAW handled by compiler waitcnt; no barrier needed.
    }

    double mem_lo = 0.0, syn_lo = 0.0, trc_lo = 0.0, refr_lo = 0.0, rec_lo = 0.0;
    double mem_hi = 0.0, syn_hi = 0.0, trc_hi = 0.0, refr_hi = 0.0, rec_hi = 0.0;

    double x_lo[XCHUNK], x_hi[XCHUNK];

    for (int t0 = 0; t0 < nt; t0 += XCHUNK) {
        const int cs = (nt - t0 < XCHUNK) ? (nt - t0) : XCHUNK;
        // Prefetch cs steps of input current: 2*cs independent loads, one wait.
        #pragma unroll
        for (int s = 0; s < XCHUNK; ++s) {
            if (s < cs) {
                x_lo[s] = inp_cur[(size_t)(t0 + s) * 128 + l];
                x_hi[s] = inp_cur[(size_t)(t0 + s) * 128 + l + 64];
            }
        }

        #pragma unroll
        for (int s = 0; s < XCHUNK; ++s) {
            if (s >= cs) break;
            const int t = t0 + s;

            syn_lo = syn_lo * (1.0 - 1.0 / 5.0) + x_lo[s] + rec_lo;
            mem_lo = mem_lo * (1.0 - 1.0 / 10.0) + syn_lo / 10.0;
            if (refr_lo > 0.0) mem_lo = 0.0;
            refr_lo = refr_lo - 1.0;
            if (refr_lo < 0.0) refr_lo = 0.0;
            const bool sp_lo = mem_lo > 1.0;

            syn_hi = syn_hi * (1.0 - 1.0 / 5.0) + x_hi[s] + rec_hi;
            mem_hi = mem_hi * (1.0 - 1.0 / 10.0) + syn_hi / 10.0;
            if (refr_hi > 0.0) mem_hi = 0.0;
            refr_hi = refr_hi - 1.0;
            if (refr_hi < 0.0) refr_hi = 0.0;
            const bool sp_hi = mem_hi > 1.0;

            // Wave-uniform spike masks (rows 0-63 and 64-127), in SGPRs.
            const unsigned long long m0 = __ballot(sp_lo);
            const unsigned long long m1 = __ballot(sp_hi);

            if (sp_lo) { mem_lo = 0.0; refr_lo += 2.0; }
            trc_lo = trc_lo * 0.95 + (sp_lo ? 1.0 : 0.0);
            if (sp_hi) { mem_hi = 0.0; refr_hi += 2.0; }
            trc_hi = trc_hi * 0.95 + (sp_hi ? 1.0 : 0.0);

            spk_out[(size_t)t * 128 + l]      = sp_lo ? 1.0f : 0.0f;
            spk_out[(size_t)t * 128 + l + 64] = sp_hi ? 1.0f : 0.0f;
            mem_out[(size_t)t * 128 + l]      = (float)mem_lo;
            mem_out[(size_t)t * 128 + l + 64] = (float)mem_hi;

            // Sparse recurrent gather: rows ascending (m0 then m1), batches
            // of 4 so 8 LDS reads are in flight before one wait. Padded
            // slots add exact +0.0 (no effect on the f64 sum).
            double add_lo = 0.0, add_hi = 0.0;
            #pragma unroll 1
            for (int half = 0; half < 2; ++half) {
                unsigned long long m = half ? m1 : m0;
                const float* wb = lds_w + (half ? (64 * 128) : 0);
                while (m) {
                    int kk[4];
                    bool vv[4];
                    #pragma unroll
                    for (int j = 0; j < 4; ++j) {
                        vv[j] = (m != 0ull);
                        kk[j] = m ? (int)__builtin_ctzll(m) : 0;
                        m &= (m - 1ull);
                    }
                    float wl[4], wh[4];
                    #pragma unroll
                    for (int j = 0; j < 4; ++j) {
                        wl[j] = wb[kk[j] * 128 + l];
                        wh[j] = wb[kk[j] * 128 + l + 64];
                    }
                    #pragma unroll
                    for (int j = 0; j < 4; ++j) {
                        add_lo += vv[j] ? (double)wl[j] : 0.0;
                        add_hi += vv[j] ? (double)wh[j] : 0.0;
                    }
                }
            }
            rec_lo = rec_lo * 0.95 + add_lo;
            rec_hi = rec_hi * 0.95 + add_hi;
        }
    }
    trace_out[l]      = (float)trc_lo;
    trace_out[l + 64] = (float)trc_hi;
}

// ---------------------------------------------------------------------------
// Kernel 3: broadcast row 0 -> rows 1..B-1 (spikes + membrane).
// 4 vf4s/thread, nontemporal streaming stores.
// ---------------------------------------------------------------------------
__global__ void bcast_kernel(float* __restrict__ out,
                             int TN4, long long TN, long long B_TN) {
    const long long b = (long long)blockIdx.y + 1;
    const int base = blockIdx.x * (blockDim.x * 4) + threadIdx.x;
    const vf4* s0 = (const vf4*)out;
    const vf4* m0 = (const vf4*)(out + B_TN);
    vf4* sd = (vf4*)(out + b * TN);
    vf4* md = (vf4*)(out + B_TN + b * TN);
    #pragma unroll
    for (int j = 0; j < 4; ++j) {
        const int i = base + j * blockDim.x;
        if (i < TN4) {
            __builtin_nontemporal_store(s0[i], &sd[i]);
            __builtin_nontemporal_store(m0[i], &md[i]);
        }
    }
}

// ---------------------------------------------------------------------------
// Kernel 4: broadcast final trace row 0 -> rows 1..B-1.
// ---------------------------------------------------------------------------
__global__ void trace_bcast_kernel(float* __restrict__ tr, int B, int N4) {
    const int idx = blockIdx.x * blockDim.x + threadIdx.x;
    const int total = (B - 1) * N4;
    if (idx >= total) return;
    const int b = idx / N4 + 1;
    const int j = idx - (b - 1) * N4;
    const vf4 v = ((const vf4*)tr)[j];
    __builtin_nontemporal_store(v, &((vf4*)(tr + (size_t)b * N4 * 4))[j]);
}

// ---------------------------------------------------------------------------
extern "C" void kernel_launch(void* const* d_in, const int* in_sizes, int n_in,
                              void* d_out, int out_size, void* d_ws, size_t ws_size,
                              hipStream_t stream) {
    const float* sig  = (const float*)d_in[0];  // (T, D)
    const float* win  = (const float*)d_in[1];  // (D, N)
    const float* wrec = (const float*)d_in[2];  // (N, N)

    int N = 1;
    while ((long long)N * N < (long long)in_sizes[2]) ++N;   // N = 128
    const int D = in_sizes[1] / N;                            // 64
    const int B = in_sizes[0] / D;                            // 1000 (= T)
    const int nt = (int)((((long long)out_size / B) - N) / (2 * N));  // 1000

    const long long TN   = (long long)nt * N;   // 128,000
    const long long B_TN = (long long)B * TN;   // 128,000,000

    float* out = (float*)d_out;
    // f64 inp_cur scratch in the tail of d_out (overwritten later by the
    // broadcasts, after sim has consumed it).
    double* inp_cur = (double*)(out + ((size_t)out_size - 2 * (size_t)TN));

    inpcur_kernel<<<nt, N, 0, stream>>>(sig, win, inp_cur, D, N);

    sim_kernel<<<1, 64, 0, stream>>>(inp_cur, wrec,
                                     out,              // spikes row 0
                                     out + B_TN,       // membrane row 0
                                     out + 2 * B_TN,   // trace row 0
                                     nt);

    const int TN4 = (int)(TN / 4);                    // 32,000
    dim3 bgrid((TN4 + 1023) / 1024, B - 1);
    bcast_kernel<<<bgrid, 256, 0, stream>>>(out, TN4, TN, B_TN);

    const int trace_total = (B - 1) * (N / 4);
    trace_bcast_kernel<<<(trace_total + 255) / 256, 256, 0, stream>>>(
        out + 2 * B_TN, B, N / 4);
}